// Round 5
// baseline (388.770 us; speedup 1.0000x reference)
//
#include <hip/hip_runtime.h>
#include <math.h>

#define D_MODEL 1024
#define HEADS   16
#define HDIM    64
#define CHUNK   128
#define B_SZ    4
#define L_SEQ   2048
#define NCHUNK  16
#define NTOK    8192
#define EPS_DEN 1e-3f

typedef _Float16 half8 __attribute__((ext_vector_type(8)));
typedef float    f32x4 __attribute__((ext_vector_type(4)));

__device__ __forceinline__ void gld_lds16(const void* g, void* l) {
    __builtin_amdgcn_global_load_lds(
        (const __attribute__((address_space(1))) void*)g,
        (__attribute__((address_space(3))) void*)l, 16, 0, 0);
}

// ---------------------------------------------------------------------------
// Fused preprocessing: x->hi|lo, Wq->hi|lo, Wk->hi|lo, Wv->f16, Wo->f16,
// bias concat [bq|bk].
// ---------------------------------------------------------------------------
__global__ __launch_bounds__(256) void prep(
    const float* __restrict__ x,  const float* __restrict__ Wq,
    const float* __restrict__ Wk, const float* __restrict__ Wv,
    const float* __restrict__ Wo, const float* __restrict__ bq,
    const float* __restrict__ bk,
    _Float16* __restrict__ x2,  _Float16* __restrict__ w2q,
    _Float16* __restrict__ w2k, _Float16* __restrict__ wv16,
    _Float16* __restrict__ wo16, float* __restrict__ bqk) {
    const int bid = blockIdx.x;
    if (bid < 5120) {           // split jobs: x / Wq / Wk
        const float* src; _Float16* dst; int t;
        if (bid < 4096)      { src = x;  dst = x2;  t = bid * 256 + threadIdx.x; }
        else if (bid < 4608) { src = Wq; dst = w2q; t = (bid - 4096) * 256 + threadIdx.x; }
        else                 { src = Wk; dst = w2k; t = (bid - 4608) * 256 + threadIdx.x; }
        int m = t >> 7, kc = (t & 127) << 3;
        const float* s = src + (size_t)m * 1024 + kc;
        f32x4 a = *(const f32x4*)s;
        f32x4 b = *(const f32x4*)(s + 4);
        float xs[8] = {a.x, a.y, a.z, a.w, b.x, b.y, b.z, b.w};
        half8 hi, lo;
        #pragma unroll
        for (int u = 0; u < 8; ++u) {
            _Float16 h = (_Float16)xs[u];
            hi[u] = h;
            lo[u] = (_Float16)(xs[u] - (float)h);
        }
        *(half8*)(dst + (size_t)m * 2048 + kc)        = hi;
        *(half8*)(dst + (size_t)m * 2048 + 1024 + kc) = lo;
    } else if (bid < 6144) {    // conv jobs: Wv / Wo
        const float* src; _Float16* dst; int t;
        if (bid < 5632) { src = Wv; dst = wv16; t = (bid - 5120) * 256 + threadIdx.x; }
        else            { src = Wo; dst = wo16; t = (bid - 5632) * 256 + threadIdx.x; }
        int m = t >> 7, kc = (t & 127) << 3;
        const float* s = src + (size_t)m * 1024 + kc;
        f32x4 a = *(const f32x4*)s;
        f32x4 b = *(const f32x4*)(s + 4);
        float xs[8] = {a.x, a.y, a.z, a.w, b.x, b.y, b.z, b.w};
        half8 hv;
        #pragma unroll
        for (int u = 0; u < 8; ++u) hv[u] = (_Float16)xs[u];
        *(half8*)(dst + (size_t)m * 1024 + kc) = hv;
    } else {
        int i = (bid - 6144) * 256 + threadIdx.x;
        bqk[i] = (i < 1024) ? bq[i] : bk[i - 1024];
    }
}

// ---------------------------------------------------------------------------
// Fused q/k/v projection GEMM.
// grid dim3(24, 64): blockIdx.x = col-block (fastest -> XCD col-pinning),
//                    blockIdx.y = row-block.
// cb 0..15 : q/k split GEMM, K=3072 logical [hi*hi|lo*hi|hi*lo], silu,
//            writes fp32 (direct) + f16 (slab transpose).
// cb 16..23: v plain f16 GEMM, K=1024 (hi half of x2), f16 slab only.
// ---------------------------------------------------------------------------
__global__ __launch_bounds__(256, 4) void gemm_qkv(
    const _Float16* __restrict__ A,    // x2, lda 2048
    const _Float16* __restrict__ Bqk,  // [w2q;w2k], ldb 2048
    const _Float16* __restrict__ Bv,   // wv16, ldb 1024
    const float* __restrict__ bqk, const float* __restrict__ bv,
    float* __restrict__ Q32, float* __restrict__ K32,
    _Float16* __restrict__ Q16, _Float16* __restrict__ K16,
    _Float16* __restrict__ V16) {
    __shared__ __align__(16) _Float16 sA[4096];
    __shared__ __align__(16) _Float16 sB[4096];
    __shared__ __align__(16) _Float16 sC16[32 * 136];

    const int cb   = blockIdx.x;
    const int isqk = (cb < 16);
    const int tid  = threadIdx.x;
    const int lane = tid & 63;
    const int w    = tid >> 6;
    const int row0 = blockIdx.y * 128;
    const int col0 = cb * 128;               // 0..3071 global col space
    const int wm   = (w & 1) * 64;
    const int wn   = (w >> 1) * 64;

    const _Float16* B = isqk ? Bqk : Bv;
    const int ldb     = isqk ? 2048 : 1024;
    const int bcol0   = isqk ? col0 : col0 - 2048;
    const int kits    = isqk ? 96 : 32;

    const int ch0 = w * 64 + lane;
    const int rS0 = ch0 >> 2;
    const int cS0 = (ch0 & 3) ^ ((rS0 >> 1) & 3);
    const int ch1 = ch0 + 256;
    const int rS1 = ch1 >> 2;
    const int cS1 = (ch1 & 3) ^ ((rS1 >> 1) & 3);

    f32x4 acc[4][4];
    #pragma unroll
    for (int i = 0; i < 4; ++i)
        #pragma unroll
        for (int j = 0; j < 4; ++j) { f32x4 z = {0.f, 0.f, 0.f, 0.f}; acc[i][j] = z; }

    const int ml = lane & 15;
    const int kg = lane >> 4;
    int offA[4], offB[4];
    #pragma unroll
    for (int i = 0; i < 4; ++i) {
        int r  = wm + i * 16 + ml;
        offA[i] = r * 32 + (kg ^ ((r >> 1) & 3)) * 8;
        int rn = wn + i * 16 + ml;
        offB[i] = rn * 32 + (kg ^ ((rn >> 1) & 3)) * 8;
    }

    for (int kit = 0; kit < kits; ++kit) {
        const int k0   = kit * 32;
        const int acol = (k0 < 2048) ? k0 : k0 - 2048;
        const int bcol = (k0 < 1024) ? k0 : k0 - 1024;

        gld_lds16(A + (size_t)(row0 + rS0) * 2048 + acol + cS0 * 8, &sA[w * 512]);
        gld_lds16(A + (size_t)(row0 + rS1) * 2048 + acol + cS1 * 8, &sA[2048 + w * 512]);
        gld_lds16(B + (size_t)(bcol0 + rS0) * ldb + bcol + cS0 * 8, &sB[w * 512]);
        gld_lds16(B + (size_t)(bcol0 + rS1) * ldb + bcol + cS1 * 8, &sB[2048 + w * 512]);
        __syncthreads();

        half8 af[4], bf[4];
        #pragma unroll
        for (int i = 0; i < 4; ++i) {
            af[i] = *(const half8*)&sA[offA[i]];
            bf[i] = *(const half8*)&sB[offB[i]];
        }
        #pragma unroll
        for (int i = 0; i < 4; ++i)
            #pragma unroll
            for (int j = 0; j < 4; ++j)
                acc[i][j] = __builtin_amdgcn_mfma_f32_16x16x32_f16(af[i], bf[j], acc[i][j], 0, 0, 0);
        __syncthreads();
    }

    // output routing
    const int colq = isqk ? ((col0 < 1024) ? col0 : col0 - 1024) : (col0 - 2048);
    float*    Y32  = (col0 < 1024) ? Q32 : K32;      // only used when isqk
    _Float16* Y16  = isqk ? ((col0 < 1024) ? Q16 : K16) : V16;

    const int rg = lane >> 4;
    #pragma unroll
    for (int j = 0; j < 4; ++j) {
        const float bvb = isqk ? bqk[col0 + wn + j * 16 + ml]
                               : bv[colq + wn + j * 16 + ml];
        const int nn = colq + wn + j * 16 + ml;
        #pragma unroll
        for (int i = 0; i < 4; ++i) {
            #pragma unroll
            for (int t = 0; t < 4; ++t) {
                float vv = acc[i][j][t] + bvb;
                if (isqk) {
                    vv = vv / (1.f + expf(-vv));     // silu
                    int mm = row0 + wm + i * 16 + rg * 4 + t;
                    Y32[(size_t)mm * 1024 + nn] = vv;
                }
                acc[i][j][t] = vv;
            }
        }
    }
    // f16 via LDS slab transpose (4 slabs of 32 rows)
    for (int s = 0; s < 4; ++s) {
        if ((wm == 0) == (s < 2)) {
            const int ib = (s & 1) * 2;
            #pragma unroll
            for (int ii = 0; ii < 2; ++ii)
                #pragma unroll
                for (int j = 0; j < 4; ++j)
                    #pragma unroll
                    for (int t = 0; t < 4; ++t) {
                        int lr = ii * 16 + rg * 4 + t;
                        sC16[lr * 136 + wn + j * 16 + ml] = (_Float16)acc[ib + ii][j][t];
                    }
        }
        __syncthreads();
        #pragma unroll
        for (int u = 0; u < 2; ++u) {
            int c = u * 256 + tid;
            int r = c >> 4, cc = (c & 15) * 8;
            half8 hv = *(const half8*)&sC16[r * 136 + cc];
            *(half8*)(Y16 + (size_t)(row0 + 32 * s + r) * 1024 + colq + cc) = hv;
        }
        __syncthreads();
    }
}

// ---------------------------------------------------------------------------
// Final output GEMM: out = attn16 * wo16^T * 64 + bo. Tile 128x64, BK=32,
// 4 waves each 32x64. grid dim3(16, 64) = 1024 blocks, 12 KB LDS.
// ---------------------------------------------------------------------------
__global__ __launch_bounds__(256, 4) void gemm_out(
    const _Float16* __restrict__ A,   // attn16, lda 1024
    const _Float16* __restrict__ B,   // wo16, ldb 1024
    const float* __restrict__ bias,
    float* __restrict__ Y) {
    __shared__ __align__(16) _Float16 sA[4096];   // 128 x 32
    __shared__ __align__(16) _Float16 sB[2048];   // 64 x 32

    const int tid  = threadIdx.x;
    const int lane = tid & 63;
    const int w    = tid >> 6;
    const int col0 = blockIdx.x * 64;
    const int row0 = blockIdx.y * 128;

    // A staging: 512 chunks (2/thread); B staging: 256 chunks (1/thread)
    const int ch0 = w * 64 + lane;
    const int rS0 = ch0 >> 2;
    const int cS0 = (ch0 & 3) ^ ((rS0 >> 1) & 3);
    const int ch1 = ch0 + 256;
    const int rS1 = ch1 >> 2;
    const int cS1 = (ch1 & 3) ^ ((rS1 >> 1) & 3);

    f32x4 acc[2][4];
    #pragma unroll
    for (int i = 0; i < 2; ++i)
        #pragma unroll
        for (int j = 0; j < 4; ++j) { f32x4 z = {0.f, 0.f, 0.f, 0.f}; acc[i][j] = z; }

    const int ml = lane & 15;
    const int kg = lane >> 4;
    int offA[2], offB[4];
    #pragma unroll
    for (int i = 0; i < 2; ++i) {
        int r  = w * 32 + i * 16 + ml;
        offA[i] = r * 32 + (kg ^ ((r >> 1) & 3)) * 8;
    }
    #pragma unroll
    for (int j = 0; j < 4; ++j) {
        int rn = j * 16 + ml;
        offB[j] = rn * 32 + (kg ^ ((rn >> 1) & 3)) * 8;
    }

    for (int kit = 0; kit < 32; ++kit) {
        const int k0 = kit * 32;
        gld_lds16(A + (size_t)(row0 + rS0) * 1024 + k0 + cS0 * 8, &sA[w * 512]);
        gld_lds16(A + (size_t)(row0 + rS1) * 1024 + k0 + cS1 * 8, &sA[2048 + w * 512]);
        gld_lds16(B + (size_t)(col0 + rS0) * 1024 + k0 + cS0 * 8, &sB[w * 512]);
        __syncthreads();

        half8 af[2], bf[4];
        #pragma unroll
        for (int i = 0; i < 2; ++i) af[i] = *(const half8*)&sA[offA[i]];
        #pragma unroll
        for (int j = 0; j < 4; ++j) bf[j] = *(const half8*)&sB[offB[j]];
        #pragma unroll
        for (int i = 0; i < 2; ++i)
            #pragma unroll
            for (int j = 0; j < 4; ++j)
                acc[i][j] = __builtin_amdgcn_mfma_f32_16x16x32_f16(af[i], bf[j], acc[i][j], 0, 0, 0);
        __syncthreads();
    }

    const int rg = lane >> 4;
    #pragma unroll
    for (int j = 0; j < 4; ++j) {
        const int nn = col0 + j * 16 + ml;
        const float bvb = bias[nn];
        #pragma unroll
        for (int i = 0; i < 2; ++i) {
            #pragma unroll
            for (int t = 0; t < 4; ++t) {
                int mm = row0 + w * 32 + i * 16 + rg * 4 + t;
                Y[(size_t)mm * 1024 + nn] = acc[i][j][t] * 64.f + bvb;
            }
        }
    }
}

// ---------------------------------------------------------------------------
// chunk stats: kvT[blk][e][f] = sum_j v16[j][e]*k16[j][f] via MFMA;
// ksum[blk][f] fp32 from kf32 (precision-critical, feeds z -> den).
// ---------------------------------------------------------------------------
__global__ __launch_bounds__(256) void chunk_stats(
    const _Float16* __restrict__ k16g, const _Float16* __restrict__ v16g,
    const float* __restrict__ kf32,
    float* __restrict__ kvT, float* __restrict__ ksum) {
    const int blk = blockIdx.x;
    const int n = blk & 15, bh = blk >> 4, h = bh & 15, b = bh >> 4;
    const size_t base = ((size_t)b * L_SEQ + (size_t)n * CHUNK) * D_MODEL + (size_t)h * HDIM;

    __shared__ __align__(16) _Float16 sv[64 * 136];
    __shared__ __align__(16) _Float16 sk[64 * 136];
    __shared__ float sred[4 * 64];

    const int tid = threadIdx.x;
    #pragma unroll
    for (int p = 0; p < 4; ++p) {
        int idx = p * 256 + tid;
        int j = idx >> 3, c = idx & 7;
        half8 vv = *(const half8*)(v16g + base + (size_t)j * D_MODEL + c * 8);
        half8 kk = *(const half8*)(k16g + base + (size_t)j * D_MODEL + c * 8);
        #pragma unroll
        for (int u = 0; u < 8; ++u) {
            sv[(c * 8 + u) * 136 + j] = vv[u];
            sk[(c * 8 + u) * 136 + j] = kk[u];
        }
    }
    __syncthreads();

    const int lane = tid & 63;
    const int w    = tid >> 6;
    const int ml   = lane & 15;
    const int kg   = lane >> 4;

    f32x4 acc[4];
    #pragma unroll
    for (int ft = 0; ft < 4; ++ft) { f32x4 z = {0.f,0.f,0.f,0.f}; acc[ft] = z; }
    #pragma unroll
    for (int ft = 0; ft < 4; ++ft)
        #pragma unroll
        for (int kit = 0; kit < 4; ++kit) {
            half8 af = *(const half8*)&sv[(w * 16 + ml) * 136 + kit * 32 + kg * 8];
            half8 bf = *(const half8*)&sk[(ft * 16 + ml) * 136 + kit * 32 + kg * 8];
            acc[ft] = __builtin_amdgcn_mfma_f32_16x16x32_f16(af, bf, acc[ft], 0, 0, 0);
        }
    float* o = kvT + (size_t)blk * 4096;
    #pragma unroll
    for (int ft = 0; ft < 4; ++ft)
        #pragma unroll
        for (int t = 0; t < 4; ++t) {
            int e = w * 16 + kg * 4 + t;
            o[e * 64 + ft * 16 + ml] = acc[ft][t];
        }

    float s = 0.f;
    for (int j = w * 32; j < w * 32 + 32; ++j)
        s += kf32[base + (size_t)j * D_MODEL + lane];
    sred[w * 64 + lane] = s;
    __syncthreads();
    if (tid < 64)
        ksum[(size_t)blk * 64 + tid] = sred[tid] + sred[64 + tid] + sred[128 + tid] + sred[192 + tid];
}

// ---------------------------------------------------------------------------
// Exclusive cumsum over chunk axis. 1024 blocks: bh = blk>>4, seg = blk&15.
// ---------------------------------------------------------------------------
__global__ __launch_bounds__(256) void scan_chunks(float* __restrict__ kvT,
                                                   float* __restrict__ ksum) {
    const int bh  = blockIdx.x >> 4;
    const int seg = blockIdx.x & 15;
    const int idx = seg * 256 + threadIdx.x;
    float* base = kvT + (size_t)bh * NCHUNK * 4096 + idx;
    float run = 0.f;
    #pragma unroll
    for (int nn = 0; nn < NCHUNK; ++nn) {
        float t = base[(size_t)nn * 4096];
        base[(size_t)nn * 4096] = run;
        run += t;
    }
    if (seg == 0 && threadIdx.x < 64) {
        float* zb = ksum + (size_t)bh * NCHUNK * 64 + threadIdx.x;
        float r2 = 0.f;
        #pragma unroll
        for (int nn = 0; nn < NCHUNK; ++nn) {
            float t = zb[nn * 64];
            zb[nn * 64] = r2;
            r2 += t;
        }
    }
}

// ---------------------------------------------------------------------------
// den[b,h,l] = q_l . (cumsum_{j<=l} k_j)  — all fp32 (precision-critical).
// ---------------------------------------------------------------------------
__global__ __launch_bounds__(256) void den_kernel(
    const float* __restrict__ qf32, const float* __restrict__ kf32,
    const float* __restrict__ zg, float* __restrict__ deng) {
    const int blk = blockIdx.x;
    const int n = blk & 15, bh = blk >> 4, h = bh & 15, b = bh >> 4;
    const size_t base = ((size_t)b * L_SEQ + (size_t)n * CHUNK) * D_MODEL + (size_t)h * HDIM;

    __shared__ float skk[128 * 64];
    __shared__ float part[4 * 64];

    const int tid = threadIdx.x;
    #pragma unroll
    for (int p = 0; p < 8; ++p) {
        int idx = p * 256 + tid;
        int j = idx >> 4, fc = (idx & 15) * 4;
        *(f32x4*)&skk[j * 64 + fc] = *(const f32x4*)(kf32 + base + (size_t)j * D_MODEL + fc);
    }
    __syncthreads();

    const int w = tid >> 6, lane = tid & 63;
    float ps = 0.f;
    for (int j = w * 32; j < w * 32 + 32; ++j) ps += skk[j * 64 + lane];
    part[w * 64 + lane] = ps;
    __syncthreads();

    float acc = zg[(size_t)blk * 64 + lane];
    for (int w2 = 0; w2 < w; ++w2) acc += part[w2 * 64 + lane];

    float* dout = deng + ((size_t)(b * 16 + h)) * L_SEQ + n * CHUNK;
    for (int jj = 0; jj < 32; ++jj) {
        int j = w * 32 + jj;
        acc += skk[j * 64 + lane];
        float d = qf32[base + (size_t)j * D_MODEL + lane] * acc;
        #pragma unroll
        for (int off = 32; off > 0; off >>= 1) d += __shfl_xor(d, off, 64);
        if (lane == 0) dout[j] = d;
    }
}

// ---------------------------------------------------------------------------
// MFMA attention core (unchanged).
// ---------------------------------------------------------------------------
__global__ __launch_bounds__(256) void attn_core(
    const _Float16* __restrict__ q16g, const _Float16* __restrict__ k16g,
    const _Float16* __restrict__ v16g, const float* __restrict__ STg,
    const float* __restrict__ deng, _Float16* __restrict__ O16) {
    const int blk = blockIdx.x;
    const int n = blk & 15, bh = blk >> 4, h = bh & 15, b = bh >> 4;
    const size_t base = ((size_t)b * L_SEQ + (size_t)n * CHUNK) * D_MODEL + (size_t)h * HDIM;

    __shared__ __align__(16) _Float16 sq [128 * 72];
    __shared__ __align__(16) _Float16 sk [128 * 72];
    __shared__ __align__(16) _Float16 sv [64 * 136];
    __shared__ __align__(16) _Float16 sS [64 * 72];
    __shared__ __align__(16) _Float16 ssc[64 * 136];
    __shared__ float sden[128];

    const int tid = threadIdx.x;
    #pragma unroll
    for (int p = 0; p < 4; ++p) {
        int idx = p * 256 + tid;
        int j = idx >> 3, c = idx & 7;
        *(half8*)&sq[j * 72 + c * 8] = *(const half8*)(q16g + base + (size_t)j * D_MODEL + c * 8);
        *(half8*)&sk[j * 72 + c * 8] = *(const half8*)(k16g + base + (size_t)j * D_MODEL + c * 8);
        half8 vv = *(const half8*)(v16g + base + (size_t)j * D_MODEL + c * 8);
        #pragma unroll
        for (int u = 0; u < 8; ++u) sv[(c * 8 + u) * 136 + j] = vv[u];
    }
    #pragma unroll
    for (int p = 0; p < 2; ++p) {
        int idx = p * 256 + tid;
        int e = idx >> 3, c = idx & 7;
        f32x4 a = *(const f32x4*)(STg + (size_t)blk * 4096 + e * 64 + c * 8);
        f32x4 b4 = *(const f32x4*)(STg + (size_t)blk * 4096 + e * 64 + c * 8 + 4);
        half8 hv;
        hv[0] = (_Float16)a.x;  hv[1] = (_Float16)a.y;
        hv[2] = (_Float16)a.z;  hv[3] = (_Float16)a.w;
        hv[4] = (_Float16)b4.x; hv[5] = (_Float16)b4.y;
        hv[6] = (_Float16)b4.z; hv[7] = (_Float16)b4.w;
        *(half8*)&sS[e * 72 + c * 8] = hv;
    }
    if (tid < 128) sden[tid] = deng[((size_t)(b * 16 + h)) * L_SEQ + n * CHUNK + tid];
    __syncthreads();

    const int lane = tid & 63;
    const int w    = tid >> 6;
    const int ml   = lane & 15;
    const int kg   = lane >> 4;

    for (int h2 = 0; h2 < 2; ++h2) {
        const int r0 = h2 * 64 + w * 16;
        const int rowmax = r0 + 15;

        f32x4 acc1[8];
        #pragma unroll
        for (int nt = 0; nt < 8; ++nt) { f32x4 z = {0.f,0.f,0.f,0.f}; acc1[nt] = z; }
        #pragma unroll
        for (int nt = 0; nt < 8; ++nt) {
            if (nt * 16 <= rowmax) {
                #pragma unroll
                for (int kit = 0; kit < 2; ++kit) {
                    half8 af = *(const half8*)&sq[(r0 + ml) * 72 + kit * 32 + kg * 8];
                    half8 bf = *(const half8*)&sk[(nt * 16 + ml) * 72 + kit * 32 + kg * 8];
                    acc1[nt] = __builtin_amdgcn_mfma_f32_16x16x32_f16(af, bf, acc1[nt], 0, 0, 0);
                }
            }
        }
        #pragma unroll
        for (int nt = 0; nt < 8; ++nt) {
            #pragma unroll
            for (int t = 0; t < 4; ++t) {
                int lr = w * 16 + kg * 4 + t;
                int ig = h2 * 64 + lr;
                int jg = nt * 16 + ml;
                float val = (jg <= ig) ? acc1[nt][t] : 0.f;
                ssc[lr * 136 + jg] = (_Float16)val;
            }
        }
        __syncthreads();

        f32x4 acc2[4];
        #pragma unroll
        for (int et = 0; et < 4; ++et) { f32x4 z = {0.f,0.f,0.f,0.f}; acc2[et] = z; }
        const int nkit = (h2 == 0) ? 2 : 4;
        #pragma unroll
        for (int et = 0; et < 4; ++et) {
            for (int kit = 0; kit < nkit; ++kit) {
                half8 af = *(const half8*)&ssc[(w * 16 + ml) * 136 + kit * 32 + kg * 8];
                half8 bf = *(const half8*)&sv[(et * 16 + ml) * 136 + kit * 32 + kg * 8];
                acc2[et] = __builtin_amdgcn_mfma_f32_16x16x32_f16(af, bf, acc2[et], 0, 0, 0);
            }
            #pragma unroll
            for (int kit = 0; kit < 2; ++kit) {
                half8 af = *(const half8*)&sq[(r0 + ml) * 72 + kit * 32 + kg * 8];
                half8 bf = *(const half8*)&sS[(et * 16 + ml) * 72 + kit * 32 + kg * 8];
                acc2[et] = __builtin_amdgcn_mfma_f32_16x16x32_f16(af, bf, acc2[et], 0, 0, 0);
            }
        }
        #pragma unroll
        for (int t = 0; t < 4; ++t) {
            int lr = w * 16 + kg * 4 + t;
            int ig = h2 * 64 + lr;
            float rc = 0.015625f / fmaxf(sden[ig], EPS_DEN);
            #pragma unroll
            for (int et = 0; et < 4; ++et) {
                int e = et * 16 + ml;
                O16[base + (size_t)ig * D_MODEL + e] = (_Float16)(acc2[et][t] * rc);
            }
        }
        __syncthreads();
    }
}

// ---------------------------------------------------------------------------
extern "C" void kernel_launch(void* const* d_in, const int* in_sizes, int n_in,
                              void* d_out, int out_size, void* d_ws, size_t ws_size,
                              hipStream_t stream) {
    const float* x  = (const float*)d_in[0];
    const float* Wq = (const float*)d_in[1];
    const float* bq = (const float*)d_in[2];
    const float* Wk = (const float*)d_in[3];
    const float* bk = (const float*)d_in[4];
    const float* Wv = (const float*)d_in[5];
    const float* bv = (const float*)d_in[6];
    const float* Wo = (const float*)d_in[7];
    const float* bo = (const float*)d_in[8];
    float* out = (float*)d_out;

    char* p = (char*)d_ws;
    _Float16* x2   = (_Float16*)p;  p += (size_t)NTOK * 2048 * 2;
    _Float16* w2q  = (_Float16*)p;  p += (size_t)1024 * 2048 * 2;
    _Float16* w2k  = (_Float16*)p;  p += (size_t)1024 * 2048 * 2;   // contiguous after w2q
    _Float16* wv16 = (_Float16*)p;  p += (size_t)1024 * 1024 * 2;
    _Float16* wo16 = (_Float16*)p;  p += (size_t)1024 * 1024 * 2;
    float* qf   = (float*)p;        p += (size_t)NTOK * 1024 * 4;
    float* kf   = (float*)p;        p += (size_t)NTOK * 1024 * 4;
    _Float16* q16 = (_Float16*)p;   p += (size_t)NTOK * 1024 * 2;
    _Float16* k16 = (_Float16*)p;   p += (size_t)NTOK * 1024 * 2;
    _Float16* v16 = (_Float16*)p;   p += (size_t)NTOK * 1024 * 2;
    float* kvT  = (float*)p;        p += (size_t)1024 * 4096 * 4;
    float* ksb  = (float*)p;        p += (size_t)1024 * 64 * 4;
    float* den  = (float*)p;        p += (size_t)B_SZ * HEADS * L_SEQ * 4;
    float* bqk  = (float*)p;        p += 2048 * 4;
    _Float16* attn16 = x2;  // x2 dead after gemm_qkv

    prep<<<6152, 256, 0, stream>>>(x, Wq, Wk, Wv, Wo, bq, bk,
                                   x2, w2q, w2k, wv16, wo16, bqk);

    gemm_qkv<<<dim3(24, 64), 256, 0, stream>>>(x2, w2q, wv16, bqk, bv,
                                               qf, kf, q16, k16, v16);

    chunk_stats<<<1024, 256, 0, stream>>>(k16, v16, kf, kvT, ksb);
    scan_chunks<<<1024, 256, 0, stream>>>(kvT, ksb);
    den_kernel<<<1024, 256, 0, stream>>>(qf, kf, ksb, den);
    attn_core<<<1024, 256, 0, stream>>>(q16, k16, v16, kvT, den, attn16);

    gemm_out<<<dim3(16, 64), 256, 0, stream>>>(attn16, wo16, bo, out);
}

// Round 6
// 347.751 us; speedup vs baseline: 1.1180x; 1.1180x over previous
//
#include <hip/hip_runtime.h>
#include <math.h>

#define D_MODEL 1024
#define HEADS   16
#define HDIM    64
#define CHUNK   128
#define B_SZ    4
#define L_SEQ   2048
#define NCHUNK  16
#define NTOK    8192
#define EPS_DEN 1e-3f

typedef _Float16 half8 __attribute__((ext_vector_type(8)));
typedef float    f32x4 __attribute__((ext_vector_type(4)));

__device__ __forceinline__ void gld_lds16(const void* g, void* l) {
    __builtin_amdgcn_global_load_lds(
        (const __attribute__((address_space(1))) void*)g,
        (__attribute__((address_space(3))) void*)l, 16, 0, 0);
}

// ---------------------------------------------------------------------------
// Fused preprocessing: x->hi|lo, Wq->hi|lo, Wk->hi|lo, Wv->f16, Wo->f16,
// bias concat [bq|bk].
// ---------------------------------------------------------------------------
__global__ __launch_bounds__(256) void prep(
    const float* __restrict__ x,  const float* __restrict__ Wq,
    const float* __restrict__ Wk, const float* __restrict__ Wv,
    const float* __restrict__ Wo, const float* __restrict__ bq,
    const float* __restrict__ bk,
    _Float16* __restrict__ x2,  _Float16* __restrict__ w2q,
    _Float16* __restrict__ w2k, _Float16* __restrict__ wv16,
    _Float16* __restrict__ wo16, float* __restrict__ bqk) {
    const int bid = blockIdx.x;
    if (bid < 5120) {           // split jobs: x / Wq / Wk
        const float* src; _Float16* dst; int t;
        if (bid < 4096)      { src = x;  dst = x2;  t = bid * 256 + threadIdx.x; }
        else if (bid < 4608) { src = Wq; dst = w2q; t = (bid - 4096) * 256 + threadIdx.x; }
        else                 { src = Wk; dst = w2k; t = (bid - 4608) * 256 + threadIdx.x; }
        int m = t >> 7, kc = (t & 127) << 3;
        const float* s = src + (size_t)m * 1024 + kc;
        f32x4 a = *(const f32x4*)s;
        f32x4 b = *(const f32x4*)(s + 4);
        float xs[8] = {a.x, a.y, a.z, a.w, b.x, b.y, b.z, b.w};
        half8 hi, lo;
        #pragma unroll
        for (int u = 0; u < 8; ++u) {
            _Float16 h = (_Float16)xs[u];
            hi[u] = h;
            lo[u] = (_Float16)(xs[u] - (float)h);
        }
        *(half8*)(dst + (size_t)m * 2048 + kc)        = hi;
        *(half8*)(dst + (size_t)m * 2048 + 1024 + kc) = lo;
    } else if (bid < 6144) {    // conv jobs: Wv / Wo
        const float* src; _Float16* dst; int t;
        if (bid < 5632) { src = Wv; dst = wv16; t = (bid - 5120) * 256 + threadIdx.x; }
        else            { src = Wo; dst = wo16; t = (bid - 5632) * 256 + threadIdx.x; }
        int m = t >> 7, kc = (t & 127) << 3;
        const float* s = src + (size_t)m * 1024 + kc;
        f32x4 a = *(const f32x4*)s;
        f32x4 b = *(const f32x4*)(s + 4);
        float xs[8] = {a.x, a.y, a.z, a.w, b.x, b.y, b.z, b.w};
        half8 hv;
        #pragma unroll
        for (int u = 0; u < 8; ++u) hv[u] = (_Float16)xs[u];
        *(half8*)(dst + (size_t)m * 1024 + kc) = hv;
    } else {
        int i = (bid - 6144) * 256 + threadIdx.x;
        bqk[i] = (i < 1024) ? bq[i] : bk[i - 1024];
    }
}

// ---------------------------------------------------------------------------
// Fused q/k/v projection GEMM.
// grid dim3(64, 24): blockIdx.x = ROW-block (fastest -> each XCD owns a
// row-slice; only the small B is re-read per XCD), blockIdx.y = col-block.
// cb 0..15 : q/k split GEMM, K=3072 logical [hi*hi|lo*hi|hi*lo], silu,
//            fp32 direct + f16 slab stores. k-blocks also emit ksum (fp32).
// cb 16..23: v plain f16 GEMM, K=1024 (hi half of x2), f16 slab only.
// ---------------------------------------------------------------------------
__global__ __launch_bounds__(256, 4) void gemm_qkv(
    const _Float16* __restrict__ A,    // x2, lda 2048
    const _Float16* __restrict__ Bqk,  // [w2q;w2k], ldb 2048
    const _Float16* __restrict__ Bv,   // wv16, ldb 1024
    const float* __restrict__ bqk, const float* __restrict__ bv,
    float* __restrict__ Q32, float* __restrict__ K32,
    _Float16* __restrict__ Q16, _Float16* __restrict__ K16,
    _Float16* __restrict__ V16, float* __restrict__ ksum) {
    __shared__ __align__(16) _Float16 sA[4096];
    __shared__ __align__(16) _Float16 sB[4096];
    __shared__ __align__(16) _Float16 sC16[32 * 136];
    __shared__ float sksum[2][128];

    const int cb   = blockIdx.y;
    const int isqk = (cb < 16);
    const int isk  = (cb >= 8 && cb < 16);
    const int tid  = threadIdx.x;
    const int lane = tid & 63;
    const int w    = tid >> 6;
    const int row0 = blockIdx.x * 128;
    const int col0 = cb * 128;               // 0..3071 global col space
    const int wm   = (w & 1) * 64;
    const int wn   = (w >> 1) * 64;

    const _Float16* B = isqk ? Bqk : Bv;
    const int ldb     = isqk ? 2048 : 1024;
    const int bcol0   = isqk ? col0 : col0 - 2048;
    const int kits    = isqk ? 96 : 32;

    const int ch0 = w * 64 + lane;
    const int rS0 = ch0 >> 2;
    const int cS0 = (ch0 & 3) ^ ((rS0 >> 1) & 3);
    const int ch1 = ch0 + 256;
    const int rS1 = ch1 >> 2;
    const int cS1 = (ch1 & 3) ^ ((rS1 >> 1) & 3);

    f32x4 acc[4][4];
    #pragma unroll
    for (int i = 0; i < 4; ++i)
        #pragma unroll
        for (int j = 0; j < 4; ++j) { f32x4 z = {0.f, 0.f, 0.f, 0.f}; acc[i][j] = z; }

    const int ml = lane & 15;
    const int kg = lane >> 4;
    int offA[4], offB[4];
    #pragma unroll
    for (int i = 0; i < 4; ++i) {
        int r  = wm + i * 16 + ml;
        offA[i] = r * 32 + (kg ^ ((r >> 1) & 3)) * 8;
        int rn = wn + i * 16 + ml;
        offB[i] = rn * 32 + (kg ^ ((rn >> 1) & 3)) * 8;
    }

    for (int kit = 0; kit < kits; ++kit) {
        const int k0   = kit * 32;
        const int acol = (k0 < 2048) ? k0 : k0 - 2048;
        const int bcol = (k0 < 1024) ? k0 : k0 - 1024;

        gld_lds16(A + (size_t)(row0 + rS0) * 2048 + acol + cS0 * 8, &sA[w * 512]);
        gld_lds16(A + (size_t)(row0 + rS1) * 2048 + acol + cS1 * 8, &sA[2048 + w * 512]);
        gld_lds16(B + (size_t)(bcol0 + rS0) * ldb + bcol + cS0 * 8, &sB[w * 512]);
        gld_lds16(B + (size_t)(bcol0 + rS1) * ldb + bcol + cS1 * 8, &sB[2048 + w * 512]);
        __syncthreads();

        half8 af[4], bf[4];
        #pragma unroll
        for (int i = 0; i < 4; ++i) {
            af[i] = *(const half8*)&sA[offA[i]];
            bf[i] = *(const half8*)&sB[offB[i]];
        }
        #pragma unroll
        for (int i = 0; i < 4; ++i)
            #pragma unroll
            for (int j = 0; j < 4; ++j)
                acc[i][j] = __builtin_amdgcn_mfma_f32_16x16x32_f16(af[i], bf[j], acc[i][j], 0, 0, 0);
        __syncthreads();
    }

    // output routing
    const int colq = isqk ? ((col0 < 1024) ? col0 : col0 - 1024) : (col0 - 2048);
    float*    Y32  = (col0 < 1024) ? Q32 : K32;      // only used when isqk
    _Float16* Y16  = isqk ? ((col0 < 1024) ? Q16 : K16) : V16;

    const int rg = lane >> 4;
    #pragma unroll
    for (int j = 0; j < 4; ++j) {
        const float bvb = isqk ? bqk[col0 + wn + j * 16 + ml]
                               : bv[colq + wn + j * 16 + ml];
        const int nn = colq + wn + j * 16 + ml;
        #pragma unroll
        for (int i = 0; i < 4; ++i) {
            #pragma unroll
            for (int t = 0; t < 4; ++t) {
                float vv = acc[i][j][t] + bvb;
                if (isqk) {
                    vv = vv / (1.f + expf(-vv));     // silu
                    int mm = row0 + wm + i * 16 + rg * 4 + t;
                    Y32[(size_t)mm * 1024 + nn] = vv;
                }
                acc[i][j][t] = vv;
            }
        }
    }

    // fused ksum for k-blocks: this tile = chunk (b,n) x 2 heads.
    if (isk) {
        #pragma unroll
        for (int j = 0; j < 4; ++j) {
            float ps = 0.f;
            #pragma unroll
            for (int i = 0; i < 4; ++i)
                #pragma unroll
                for (int t = 0; t < 4; ++t) ps += acc[i][j][t];
            // reduce over the 4 rg lane groups (lanes kg*16+ml)
            ps += __shfl_xor(ps, 16, 64);
            ps += __shfl_xor(ps, 32, 64);
            if (kg == 0) sksum[wm >> 6][wn + j * 16 + ml] = ps;
        }
        __syncthreads();
        if (tid < 128) {
            const int b = row0 >> 11;
            const int n = (row0 >> 7) & 15;
            const int cg = colq + tid;         // global k-col
            const int h = cg >> 6, f = cg & 63;
            ksum[(size_t)(((b * 16 + h) * 16 + n)) * 64 + f] =
                sksum[0][tid] + sksum[1][tid];
        }
        __syncthreads();
    }

    // f16 via LDS slab transpose (4 slabs of 32 rows)
    for (int s = 0; s < 4; ++s) {
        if ((wm == 0) == (s < 2)) {
            const int ib = (s & 1) * 2;
            #pragma unroll
            for (int ii = 0; ii < 2; ++ii)
                #pragma unroll
                for (int j = 0; j < 4; ++j)
                    #pragma unroll
                    for (int t = 0; t < 4; ++t) {
                        int lr = ii * 16 + rg * 4 + t;
                        sC16[lr * 136 + wn + j * 16 + ml] = (_Float16)acc[ib + ii][j][t];
                    }
        }
        __syncthreads();
        #pragma unroll
        for (int u = 0; u < 2; ++u) {
            int c = u * 256 + tid;
            int r = c >> 4, cc = (c & 15) * 8;
            half8 hv = *(const half8*)&sC16[r * 136 + cc];
            *(half8*)(Y16 + (size_t)(row0 + 32 * s + r) * 1024 + colq + cc) = hv;
        }
        __syncthreads();
    }
}

// ---------------------------------------------------------------------------
// Final output GEMM: out = attn16 * wo16^T * 64 + bo. Tile 128x64, BK=32.
// grid dim3(64, 16): x = ROW-block fastest (XCD row-slices, B re-read only).
// ---------------------------------------------------------------------------
__global__ __launch_bounds__(256, 4) void gemm_out(
    const _Float16* __restrict__ A,   // attn16, lda 1024
    const _Float16* __restrict__ B,   // wo16, ldb 1024
    const float* __restrict__ bias,
    float* __restrict__ Y) {
    __shared__ __align__(16) _Float16 sA[4096];   // 128 x 32
    __shared__ __align__(16) _Float16 sB[2048];   // 64 x 32

    const int tid  = threadIdx.x;
    const int lane = tid & 63;
    const int w    = tid >> 6;
    const int row0 = blockIdx.x * 128;
    const int col0 = blockIdx.y * 64;

    const int ch0 = w * 64 + lane;
    const int rS0 = ch0 >> 2;
    const int cS0 = (ch0 & 3) ^ ((rS0 >> 1) & 3);
    const int ch1 = ch0 + 256;
    const int rS1 = ch1 >> 2;
    const int cS1 = (ch1 & 3) ^ ((rS1 >> 1) & 3);

    f32x4 acc[2][4];
    #pragma unroll
    for (int i = 0; i < 2; ++i)
        #pragma unroll
        for (int j = 0; j < 4; ++j) { f32x4 z = {0.f, 0.f, 0.f, 0.f}; acc[i][j] = z; }

    const int ml = lane & 15;
    const int kg = lane >> 4;
    int offA[2], offB[4];
    #pragma unroll
    for (int i = 0; i < 2; ++i) {
        int r  = w * 32 + i * 16 + ml;
        offA[i] = r * 32 + (kg ^ ((r >> 1) & 3)) * 8;
    }
    #pragma unroll
    for (int j = 0; j < 4; ++j) {
        int rn = j * 16 + ml;
        offB[j] = rn * 32 + (kg ^ ((rn >> 1) & 3)) * 8;
    }

    for (int kit = 0; kit < 32; ++kit) {
        const int k0 = kit * 32;
        gld_lds16(A + (size_t)(row0 + rS0) * 1024 + k0 + cS0 * 8, &sA[w * 512]);
        gld_lds16(A + (size_t)(row0 + rS1) * 1024 + k0 + cS1 * 8, &sA[2048 + w * 512]);
        gld_lds16(B + (size_t)(col0 + rS0) * 1024 + k0 + cS0 * 8, &sB[w * 512]);
        __syncthreads();

        half8 af[2], bf[4];
        #pragma unroll
        for (int i = 0; i < 2; ++i) af[i] = *(const half8*)&sA[offA[i]];
        #pragma unroll
        for (int j = 0; j < 4; ++j) bf[j] = *(const half8*)&sB[offB[j]];
        #pragma unroll
        for (int i = 0; i < 2; ++i)
            #pragma unroll
            for (int j = 0; j < 4; ++j)
                acc[i][j] = __builtin_amdgcn_mfma_f32_16x16x32_f16(af[i], bf[j], acc[i][j], 0, 0, 0);
        __syncthreads();
    }

    const int rg = lane >> 4;
    #pragma unroll
    for (int j = 0; j < 4; ++j) {
        const int nn = col0 + j * 16 + ml;
        const float bvb = bias[nn];
        #pragma unroll
        for (int i = 0; i < 2; ++i) {
            #pragma unroll
            for (int t = 0; t < 4; ++t) {
                int mm = row0 + w * 32 + i * 16 + rg * 4 + t;
                Y[(size_t)mm * 1024 + nn] = acc[i][j][t] * 64.f + bvb;
            }
        }
    }
}

// ---------------------------------------------------------------------------
// chunk stats: kvT[blk][e][f] = sum_j v16[j][e]*k16[j][f] via MFMA.
// (ksum now produced by gemm_qkv.)
// ---------------------------------------------------------------------------
__global__ __launch_bounds__(256) void chunk_stats(
    const _Float16* __restrict__ k16g, const _Float16* __restrict__ v16g,
    float* __restrict__ kvT) {
    const int blk = blockIdx.x;
    const int n = blk & 15, bh = blk >> 4, h = bh & 15, b = bh >> 4;
    const size_t base = ((size_t)b * L_SEQ + (size_t)n * CHUNK) * D_MODEL + (size_t)h * HDIM;

    __shared__ __align__(16) _Float16 sv[64 * 136];
    __shared__ __align__(16) _Float16 sk[64 * 136];

    const int tid = threadIdx.x;
    #pragma unroll
    for (int p = 0; p < 4; ++p) {
        int idx = p * 256 + tid;
        int j = idx >> 3, c = idx & 7;
        half8 vv = *(const half8*)(v16g + base + (size_t)j * D_MODEL + c * 8);
        half8 kk = *(const half8*)(k16g + base + (size_t)j * D_MODEL + c * 8);
        #pragma unroll
        for (int u = 0; u < 8; ++u) {
            sv[(c * 8 + u) * 136 + j] = vv[u];
            sk[(c * 8 + u) * 136 + j] = kk[u];
        }
    }
    __syncthreads();

    const int lane = tid & 63;
    const int w    = tid >> 6;
    const int ml   = lane & 15;
    const int kg   = lane >> 4;

    f32x4 acc[4];
    #pragma unroll
    for (int ft = 0; ft < 4; ++ft) { f32x4 z = {0.f,0.f,0.f,0.f}; acc[ft] = z; }
    #pragma unroll
    for (int ft = 0; ft < 4; ++ft)
        #pragma unroll
        for (int kit = 0; kit < 4; ++kit) {
            half8 af = *(const half8*)&sv[(w * 16 + ml) * 136 + kit * 32 + kg * 8];
            half8 bf = *(const half8*)&sk[(ft * 16 + ml) * 136 + kit * 32 + kg * 8];
            acc[ft] = __builtin_amdgcn_mfma_f32_16x16x32_f16(af, bf, acc[ft], 0, 0, 0);
        }
    float* o = kvT + (size_t)blk * 4096;
    #pragma unroll
    for (int ft = 0; ft < 4; ++ft)
        #pragma unroll
        for (int t = 0; t < 4; ++t) {
            int e = w * 16 + kg * 4 + t;
            o[e * 64 + ft * 16 + ml] = acc[ft][t];
        }
}

// ---------------------------------------------------------------------------
// Exclusive cumsum over chunk axis. 1024 blocks: bh = blk>>4, seg = blk&15.
// ---------------------------------------------------------------------------
__global__ __launch_bounds__(256) void scan_chunks(float* __restrict__ kvT,
                                                   float* __restrict__ ksum) {
    const int bh  = blockIdx.x >> 4;
    const int seg = blockIdx.x & 15;
    const int idx = seg * 256 + threadIdx.x;
    float* base = kvT + (size_t)bh * NCHUNK * 4096 + idx;
    float run = 0.f;
    #pragma unroll
    for (int nn = 0; nn < NCHUNK; ++nn) {
        float t = base[(size_t)nn * 4096];
        base[(size_t)nn * 4096] = run;
        run += t;
    }
    if (seg == 0 && threadIdx.x < 64) {
        float* zb = ksum + (size_t)bh * NCHUNK * 64 + threadIdx.x;
        float r2 = 0.f;
        #pragma unroll
        for (int nn = 0; nn < NCHUNK; ++nn) {
            float t = zb[nn * 64];
            zb[nn * 64] = r2;
            r2 += t;
        }
    }
}

// ---------------------------------------------------------------------------
// den[b,h,l] = q_l . (cumsum_{j<=l} k_j)  — all fp32 (precision-critical).
// ---------------------------------------------------------------------------
__global__ __launch_bounds__(256) void den_kernel(
    const float* __restrict__ qf32, const float* __restrict__ kf32,
    const float* __restrict__ zg, float* __restrict__ deng) {
    const int blk = blockIdx.x;
    const int n = blk & 15, bh = blk >> 4, h = bh & 15, b = bh >> 4;
    const size_t base = ((size_t)b * L_SEQ + (size_t)n * CHUNK) * D_MODEL + (size_t)h * HDIM;

    __shared__ float skk[128 * 64];
    __shared__ float part[4 * 64];

    const int tid = threadIdx.x;
    #pragma unroll
    for (int p = 0; p < 8; ++p) {
        int idx = p * 256 + tid;
        int j = idx >> 4, fc = (idx & 15) * 4;
        *(f32x4*)&skk[j * 64 + fc] = *(const f32x4*)(kf32 + base + (size_t)j * D_MODEL + fc);
    }
    __syncthreads();

    const int w = tid >> 6, lane = tid & 63;
    float ps = 0.f;
    for (int j = w * 32; j < w * 32 + 32; ++j) ps += skk[j * 64 + lane];
    part[w * 64 + lane] = ps;
    __syncthreads();

    float acc = zg[(size_t)blk * 64 + lane];
    for (int w2 = 0; w2 < w; ++w2) acc += part[w2 * 64 + lane];

    float* dout = deng + ((size_t)(b * 16 + h)) * L_SEQ + n * CHUNK;
    for (int jj = 0; jj < 32; ++jj) {
        int j = w * 32 + jj;
        acc += skk[j * 64 + lane];
        float d = qf32[base + (size_t)j * D_MODEL + lane] * acc;
        #pragma unroll
        for (int off = 32; off > 0; off >>= 1) d += __shfl_xor(d, off, 64);
        if (lane == 0) dout[j] = d;
    }
}

// ---------------------------------------------------------------------------
// MFMA attention core (unchanged).
// ---------------------------------------------------------------------------
__global__ __launch_bounds__(256) void attn_core(
    const _Float16* __restrict__ q16g, const _Float16* __restrict__ k16g,
    const _Float16* __restrict__ v16g, const float* __restrict__ STg,
    const float* __restrict__ deng, _Float16* __restrict__ O16) {
    const int blk = blockIdx.x;
    const int n = blk & 15, bh = blk >> 4, h = bh & 15, b = bh >> 4;
    const size_t base = ((size_t)b * L_SEQ + (size_t)n * CHUNK) * D_MODEL + (size_t)h * HDIM;

    __shared__ __align__(16) _Float16 sq [128 * 72];
    __shared__ __align__(16) _Float16 sk [128 * 72];
    __shared__ __align__(16) _Float16 sv [64 * 136];
    __shared__ __align__(16) _Float16 sS [64 * 72];
    __shared__ __align__(16) _Float16 ssc[64 * 136];
    __shared__ float sden[128];

    const int tid = threadIdx.x;
    #pragma unroll
    for (int p = 0; p < 4; ++p) {
        int idx = p * 256 + tid;
        int j = idx >> 3, c = idx & 7;
        *(half8*)&sq[j * 72 + c * 8] = *(const half8*)(q16g + base + (size_t)j * D_MODEL + c * 8);
        *(half8*)&sk[j * 72 + c * 8] = *(const half8*)(k16g + base + (size_t)j * D_MODEL + c * 8);
        half8 vv = *(const half8*)(v16g + base + (size_t)j * D_MODEL + c * 8);
        #pragma unroll
        for (int u = 0; u < 8; ++u) sv[(c * 8 + u) * 136 + j] = vv[u];
    }
    #pragma unroll
    for (int p = 0; p < 2; ++p) {
        int idx = p * 256 + tid;
        int e = idx >> 3, c = idx & 7;
        f32x4 a = *(const f32x4*)(STg + (size_t)blk * 4096 + e * 64 + c * 8);
        f32x4 b4 = *(const f32x4*)(STg + (size_t)blk * 4096 + e * 64 + c * 8 + 4);
        half8 hv;
        hv[0] = (_Float16)a.x;  hv[1] = (_Float16)a.y;
        hv[2] = (_Float16)a.z;  hv[3] = (_Float16)a.w;
        hv[4] = (_Float16)b4.x; hv[5] = (_Float16)b4.y;
        hv[6] = (_Float16)b4.z; hv[7] = (_Float16)b4.w;
        *(half8*)&sS[e * 72 + c * 8] = hv;
    }
    if (tid < 128) sden[tid] = deng[((size_t)(b * 16 + h)) * L_SEQ + n * CHUNK + tid];
    __syncthreads();

    const int lane = tid & 63;
    const int w    = tid >> 6;
    const int ml   = lane & 15;
    const int kg   = lane >> 4;

    for (int h2 = 0; h2 < 2; ++h2) {
        const int r0 = h2 * 64 + w * 16;
        const int rowmax = r0 + 15;

        f32x4 acc1[8];
        #pragma unroll
        for (int nt = 0; nt < 8; ++nt) { f32x4 z = {0.f,0.f,0.f,0.f}; acc1[nt] = z; }
        #pragma unroll
        for (int nt = 0; nt < 8; ++nt) {
            if (nt * 16 <= rowmax) {
                #pragma unroll
                for (int kit = 0; kit < 2; ++kit) {
                    half8 af = *(const half8*)&sq[(r0 + ml) * 72 + kit * 32 + kg * 8];
                    half8 bf = *(const half8*)&sk[(nt * 16 + ml) * 72 + kit * 32 + kg * 8];
                    acc1[nt] = __builtin_amdgcn_mfma_f32_16x16x32_f16(af, bf, acc1[nt], 0, 0, 0);
                }
            }
        }
        #pragma unroll
        for (int nt = 0; nt < 8; ++nt) {
            #pragma unroll
            for (int t = 0; t < 4; ++t) {
                int lr = w * 16 + kg * 4 + t;
                int ig = h2 * 64 + lr;
                int jg = nt * 16 + ml;
                float val = (jg <= ig) ? acc1[nt][t] : 0.f;
                ssc[lr * 136 + jg] = (_Float16)val;
            }
        }
        __syncthreads();

        f32x4 acc2[4];
        #pragma unroll
        for (int et = 0; et < 4; ++et) { f32x4 z = {0.f,0.f,0.f,0.f}; acc2[et] = z; }
        const int nkit = (h2 == 0) ? 2 : 4;
        #pragma unroll
        for (int et = 0; et < 4; ++et) {
            for (int kit = 0; kit < nkit; ++kit) {
                half8 af = *(const half8*)&ssc[(w * 16 + ml) * 136 + kit * 32 + kg * 8];
                half8 bf = *(const half8*)&sv[(et * 16 + ml) * 136 + kit * 32 + kg * 8];
                acc2[et] = __builtin_amdgcn_mfma_f32_16x16x32_f16(af, bf, acc2[et], 0, 0, 0);
            }
            #pragma unroll
            for (int kit = 0; kit < 2; ++kit) {
                half8 af = *(const half8*)&sq[(r0 + ml) * 72 + kit * 32 + kg * 8];
                half8 bf = *(const half8*)&sS[(et * 16 + ml) * 72 + kit * 32 + kg * 8];
                acc2[et] = __builtin_amdgcn_mfma_f32_16x16x32_f16(af, bf, acc2[et], 0, 0, 0);
            }
        }
        #pragma unroll
        for (int t = 0; t < 4; ++t) {
            int lr = w * 16 + kg * 4 + t;
            int ig = h2 * 64 + lr;
            float rc = 0.015625f / fmaxf(sden[ig], EPS_DEN);
            #pragma unroll
            for (int et = 0; et < 4; ++et) {
                int e = et * 16 + ml;
                O16[base + (size_t)ig * D_MODEL + e] = (_Float16)(acc2[et][t] * rc);
            }
        }
        __syncthreads();
    }
}

// ---------------------------------------------------------------------------
extern "C" void kernel_launch(void* const* d_in, const int* in_sizes, int n_in,
                              void* d_out, int out_size, void* d_ws, size_t ws_size,
                              hipStream_t stream) {
    const float* x  = (const float*)d_in[0];
    const float* Wq = (const float*)d_in[1];
    const float* bq = (const float*)d_in[2];
    const float* Wk = (const float*)d_in[3];
    const float* bk = (const float*)d_in[4];
    const float* Wv = (const float*)d_in[5];
    const float* bv = (const float*)d_in[6];
    const float* Wo = (const float*)d_in[7];
    const float* bo = (const float*)d_in[8];
    float* out = (float*)d_out;

    char* p = (char*)d_ws;
    _Float16* x2   = (_Float16*)p;  p += (size_t)NTOK * 2048 * 2;
    _Float16* w2q  = (_Float16*)p;  p += (size_t)1024 * 2048 * 2;
    _Float16* w2k  = (_Float16*)p;  p += (size_t)1024 * 2048 * 2;   // contiguous after w2q
    _Float16* wv16 = (_Float16*)p;  p += (size_t)1024 * 1024 * 2;
    _Float16* wo16 = (_Float16*)p;  p += (size_t)1024 * 1024 * 2;
    float* qf   = (float*)p;        p += (size_t)NTOK * 1024 * 4;
    float* kf   = (float*)p;        p += (size_t)NTOK * 1024 * 4;
    _Float16* q16 = (_Float16*)p;   p += (size_t)NTOK * 1024 * 2;
    _Float16* k16 = (_Float16*)p;   p += (size_t)NTOK * 1024 * 2;
    _Float16* v16 = (_Float16*)p;   p += (size_t)NTOK * 1024 * 2;
    float* kvT  = (float*)p;        p += (size_t)1024 * 4096 * 4;
    float* ksb  = (float*)p;        p += (size_t)1024 * 64 * 4;
    float* den  = (float*)p;        p += (size_t)B_SZ * HEADS * L_SEQ * 4;
    float* bqk  = (float*)p;        p += 2048 * 4;
    _Float16* attn16 = x2;  // x2 dead after gemm_qkv

    prep<<<6152, 256, 0, stream>>>(x, Wq, Wk, Wv, Wo, bq, bk,
                                   x2, w2q, w2k, wv16, wo16, bqk);

    gemm_qkv<<<dim3(64, 24), 256, 0, stream>>>(x2, w2q, wv16, bqk, bv,
                                               qf, kf, q16, k16, v16, ksb);

    chunk_stats<<<1024, 256, 0, stream>>>(k16, v16, kvT);
    scan_chunks<<<1024, 256, 0, stream>>>(kvT, ksb);
    den_kernel<<<1024, 256, 0, stream>>>(qf, kf, ksb, den);
    attn_core<<<1024, 256, 0, stream>>>(q16, k16, v16, kvT, den, attn16);

    gemm_out<<<dim3(64, 16), 256, 0, stream>>>(attn16, wo16, bo, out);
}